// Round 1
// baseline (1241.011 us; speedup 1.0000x reference)
//
#include <hip/hip_runtime.h>

// MACE symmetric contraction (corr-3), N=2048, NL=16, C=128, E=10, P3=23, P2=4, P1=1.
// Strategy: collapse to per-(type,channel) symmetric cubic form.
//   out[n,c] = sum_{a<=b<=i} A3[t,tri,c] x_a x_b x_i
//            + sum_{a<=b}    A2[t,pr,c]  x_a x_b
//            + sum_{a}       A1[t,a,c]   x_a
// with A3 = U3sym @ W3[t] etc. Tables ~5MB -> live in L2/L3.
// Atoms grouped by type (G=4 per block) so coefficient loads amortize 4x.

constexpr int NL = 16;
constexpr int CC = 128;
constexpr int EE = 10;
constexpr int P3 = 23;
constexpr int P2 = 4;
constexpr int P1 = 1;
constexpr int NTRI = 816;   // C(18,3): a<=b<=i from 16
constexpr int NPAIR = 136;  // C(17,2): a<=b from 16
constexpr int GG = 4;       // atoms per block

// ---------------- Precompute: symmetrized U tensors ----------------
__global__ void k_symU(const float* __restrict__ U3, const float* __restrict__ U2,
                       float* __restrict__ U3s, float* __restrict__ U2s) {
    int idx = blockIdx.x * blockDim.x + threadIdx.x;
    if (idx < NTRI * P3) {
        int tri = idx / P3, k = idx % P3;
        // unrank tri -> (a<=b<=i)
        int rem = tri, a = 0;
        while (rem >= (NL - a) * (NL - a + 1) / 2) { rem -= (NL - a) * (NL - a + 1) / 2; a++; }
        int b = a;
        while (rem >= NL - b) { rem -= NL - b; b++; }
        int i = b + rem;
        auto u = [&](int p, int q, int r) { return U3[((p * NL + q) * NL + r) * P3 + k]; };
        float s = u(a,b,i) + u(a,i,b) + u(b,a,i) + u(b,i,a) + u(i,a,b) + u(i,b,a);
        // all-6-orderings sum hits each distinct permutation m times
        int m = (a == b && b == i) ? 6 : ((a == b || b == i) ? 2 : 1);
        U3s[idx] = s / (float)m;
    } else if (idx < NTRI * P3 + NPAIR * P2) {
        int j = idx - NTRI * P3;
        int pr = j / P2, k = j % P2;
        int rem = pr, a = 0;
        while (rem >= NL - a) { rem -= NL - a; a++; }
        int b = a + rem;
        float s = U2[(a * NL + b) * P2 + k];
        if (a != b) s += U2[(b * NL + a) * P2 + k];
        U2s[pr * P2 + k] = s;
    }
}

// ---------------- Precompute: per-type coefficient tables ----------------
__global__ void k_buildA(const float* __restrict__ U3s, const float* __restrict__ U2s,
                         const float* __restrict__ U1,
                         const float* __restrict__ W3, const float* __restrict__ W2,
                         const float* __restrict__ W1,
                         float* __restrict__ A3, float* __restrict__ A2, float* __restrict__ A1) {
    int b = blockIdx.x;
    int c = threadIdx.x;  // 128 threads = channels
    if (b < EE * NTRI) {
        int t = b / NTRI, tri = b % NTRI;
        float s = 0.f;
        #pragma unroll
        for (int k = 0; k < P3; k++) s += U3s[tri * P3 + k] * W3[(t * P3 + k) * CC + c];
        A3[((size_t)t * NTRI + tri) * CC + c] = s;
    } else if (b < EE * (NTRI + NPAIR)) {
        int j = b - EE * NTRI;
        int t = j / NPAIR, pr = j % NPAIR;
        float s = 0.f;
        #pragma unroll
        for (int k = 0; k < P2; k++) s += U2s[pr * P2 + k] * W2[(t * P2 + k) * CC + c];
        A2[((size_t)t * NPAIR + pr) * CC + c] = s;
    } else {
        int t = b - EE * (NTRI + NPAIR);
        for (int a = 0; a < NL; a++) {
            float s = 0.f;
            #pragma unroll
            for (int k = 0; k < P1; k++) s += U1[a * P1 + k] * W1[(t * P1 + k) * CC + c];
            A1[((size_t)t * NL + a) * CC + c] = s;
        }
    }
}

// ---------------- Atom bucketing by type ----------------
__global__ void k_zero(int* counts) {
    if (threadIdx.x < 16) counts[threadIdx.x] = 0;
}

__global__ void k_bucket(const int* __restrict__ types, int* counts, int* buckets, int N) {
    int n = blockIdx.x * blockDim.x + threadIdx.x;
    if (n < N) {
        int t = types[n];
        int pos = atomicAdd(&counts[t], 1);
        buckets[t * N + pos] = n;
    }
}

__global__ void k_groups(const int* __restrict__ counts, const int* __restrict__ buckets,
                         int* __restrict__ groups, int* __restrict__ ngroups, int N) {
    __shared__ int goff[EE + 1];
    if (threadIdx.x == 0) {
        int off = 0;
        for (int t = 0; t < EE; t++) { goff[t] = off; off += (counts[t] + GG - 1) / GG; }
        goff[EE] = off;
        *ngroups = off;
    }
    __syncthreads();
    for (int t = 0; t < EE; t++) {
        int cnt = counts[t];
        int ng = (cnt + GG - 1) / GG;
        for (int g = threadIdx.x; g < ng; g += blockDim.x) {
            int* gr = &groups[(goff[t] + g) * 8];
            int nv = cnt - g * GG; if (nv > GG) nv = GG;
            gr[0] = t;
            gr[5] = nv;
            for (int j = 0; j < GG; j++) {
                int jj = j < nv ? j : nv - 1;
                gr[1 + j] = buckets[t * N + g * GG + jj];
            }
        }
    }
}

// ---------------- Main: evaluate cubic form per (group, channel) ----------------
__global__ __launch_bounds__(CC) void k_main(const float* __restrict__ x,
                                             const float* __restrict__ A3,
                                             const float* __restrict__ A2,
                                             const float* __restrict__ A1,
                                             const int* __restrict__ groups,
                                             const int* __restrict__ ngroups,
                                             float* __restrict__ out) {
    int blk = blockIdx.x;
    if (blk >= *ngroups) return;
    const int* gr = groups + blk * 8;
    int t = gr[0];
    int n0 = gr[1], n1 = gr[2], n2 = gr[3], n3 = gr[4];
    int nvalid = gr[5];
    int c = threadIdx.x;

    float xv0[NL], xv1[NL], xv2[NL], xv3[NL];
    #pragma unroll
    for (int i = 0; i < NL; i++) {
        xv0[i] = x[((size_t)n0 * NL + i) * CC + c];
        xv1[i] = x[((size_t)n1 * NL + i) * CC + c];
        xv2[i] = x[((size_t)n2 * NL + i) * CC + c];
        xv3[i] = x[((size_t)n3 * NL + i) * CC + c];
    }

    const float* __restrict__ a3p = A3 + (size_t)t * NTRI * CC + c;
    const float* __restrict__ a2p = A2 + (size_t)t * NPAIR * CC + c;
    const float* __restrict__ a1p = A1 + (size_t)t * NL * CC + c;

    float acc0 = 0.f, acc1 = 0.f, acc2 = 0.f, acc3 = 0.f;

    // linear term
    #pragma unroll
    for (int a = 0; a < NL; a++) {
        float w = a1p[a * CC];
        acc0 += w * xv0[a]; acc1 += w * xv1[a];
        acc2 += w * xv2[a]; acc3 += w * xv3[a];
    }

    // pair + triple terms, fully unrolled so xv[] indices are compile-time
    int tri = 0, pr = 0;
    #pragma unroll
    for (int a = 0; a < NL; a++) {
        #pragma unroll
        for (int b = a; b < NL; b++) {
            float p0 = xv0[a] * xv0[b];
            float p1 = xv1[a] * xv1[b];
            float p2 = xv2[a] * xv2[b];
            float p3 = xv3[a] * xv3[b];
            float w2 = a2p[(size_t)pr * CC]; pr++;
            acc0 += w2 * p0; acc1 += w2 * p1; acc2 += w2 * p2; acc3 += w2 * p3;
            #pragma unroll
            for (int i = b; i < NL; i++) {
                float w3 = a3p[(size_t)tri * CC]; tri++;
                acc0 += w3 * (p0 * xv0[i]);
                acc1 += w3 * (p1 * xv1[i]);
                acc2 += w3 * (p2 * xv2[i]);
                acc3 += w3 * (p3 * xv3[i]);
            }
        }
    }

    if (0 < nvalid) out[(size_t)n0 * CC + c] = acc0;
    if (1 < nvalid) out[(size_t)n1 * CC + c] = acc1;
    if (2 < nvalid) out[(size_t)n2 * CC + c] = acc2;
    if (3 < nvalid) out[(size_t)n3 * CC + c] = acc3;
}

extern "C" void kernel_launch(void* const* d_in, const int* in_sizes, int n_in,
                              void* d_out, int out_size, void* d_ws, size_t ws_size,
                              hipStream_t stream) {
    const float* x   = (const float*)d_in[0];
    const int* types = (const int*)d_in[1];
    const float* U3  = (const float*)d_in[2];
    const float* U2  = (const float*)d_in[3];
    const float* U1  = (const float*)d_in[4];
    const float* W3  = (const float*)d_in[5];
    const float* W2  = (const float*)d_in[6];
    const float* W1  = (const float*)d_in[7];
    float* out = (float*)d_out;
    int N = in_sizes[1];  // atom count (2048)

    int ngmax = (N + GG - 1) / GG + EE;  // strict upper bound on group count

    // workspace layout (floats then ints), ~5.2 MB total
    float* ws   = (float*)d_ws;
    float* U3s  = ws;                         // NTRI*P3
    float* U2s  = U3s + NTRI * P3;            // NPAIR*P2
    float* A3   = U2s + NPAIR * P2;           // EE*NTRI*CC
    float* A2   = A3 + (size_t)EE * NTRI * CC;  // EE*NPAIR*CC
    float* A1   = A2 + (size_t)EE * NPAIR * CC; // EE*NL*CC
    int* counts  = (int*)(A1 + (size_t)EE * NL * CC);  // 16
    int* buckets = counts + 16;               // EE*N
    int* groups  = buckets + (size_t)EE * N;  // ngmax*8
    int* ngroups = groups + (size_t)ngmax * 8;

    int symThreads = NTRI * P3 + NPAIR * P2;
    hipLaunchKernelGGL(k_symU, dim3((symThreads + 255) / 256), dim3(256), 0, stream,
                       U3, U2, U3s, U2s);
    hipLaunchKernelGGL(k_buildA, dim3(EE * (NTRI + NPAIR) + EE), dim3(CC), 0, stream,
                       U3s, U2s, U1, W3, W2, W1, A3, A2, A1);
    hipLaunchKernelGGL(k_zero, dim3(1), dim3(64), 0, stream, counts);
    hipLaunchKernelGGL(k_bucket, dim3((N + 255) / 256), dim3(256), 0, stream,
                       types, counts, buckets, N);
    hipLaunchKernelGGL(k_groups, dim3(1), dim3(256), 0, stream,
                       counts, buckets, groups, ngroups, N);
    hipLaunchKernelGGL(k_main, dim3(ngmax), dim3(CC), 0, stream,
                       x, A3, A2, A1, groups, ngroups, out);
}

// Round 2
// 127.369 us; speedup vs baseline: 9.7434x; 9.7434x over previous
//
#include <hip/hip_runtime.h>

// MACE symmetric contraction (corr-3), N=2048, NL=16, C=128, E=10, P3=23, P2=4, P1=1.
// out[n,c] = sum_{a<=b<=i} A3[t,tri,c] x_a x_b x_i + sum_{a<=b} A2[t,pr,c] x_a x_b
//          + sum_a A1[t,a,c] x_a,  with A3 = U3sym @ W3[t] etc. (t = atom type).
// R2: float4-interleaved A3 (float2 A2), __launch_bounds__ reg cap to kill the
// R1 spill storm (227MB scratch writes), and 2-way split of the triangular nest
// per atom-group (a<4 | a>=4) with atomicAdd to double occupancy.

constexpr int NL = 16;
constexpr int CC = 128;
constexpr int EE = 10;
constexpr int P3 = 23;
constexpr int P2 = 4;
constexpr int P1 = 1;
constexpr int NTRI = 816;   // C(18,3): a<=b<=i from 16
constexpr int NPAIR = 136;  // C(17,2): a<=b from 16
constexpr int GG = 4;       // atoms per group
constexpr int ASPLIT = 4;   // nest split: a in [0,4) | [4,16)

constexpr int pairsBefore(int a) {
    int s = 0;
    for (int x = 0; x < a; x++) s += NL - x;
    return s;
}
constexpr int trisBefore(int a) {
    int s = 0;
    for (int x = 0; x < a; x++) s += (NL - x) * (NL - x + 1) / 2;
    return s;
}
static_assert(trisBefore(ASPLIT) % 4 == 0, "tri split must be float4-aligned");
static_assert(pairsBefore(ASPLIT) % 2 == 0, "pair split must be float2-aligned");

// ---------------- Precompute: symmetrized U tensors ----------------
__global__ void k_symU(const float* __restrict__ U3, const float* __restrict__ U2,
                       float* __restrict__ U3s, float* __restrict__ U2s) {
    int idx = blockIdx.x * blockDim.x + threadIdx.x;
    if (idx < NTRI * P3) {
        int tri = idx / P3, k = idx % P3;
        int rem = tri, a = 0;
        while (rem >= (NL - a) * (NL - a + 1) / 2) { rem -= (NL - a) * (NL - a + 1) / 2; a++; }
        int b = a;
        while (rem >= NL - b) { rem -= NL - b; b++; }
        int i = b + rem;
        auto u = [&](int p, int q, int r) { return U3[((p * NL + q) * NL + r) * P3 + k]; };
        float s = u(a,b,i) + u(a,i,b) + u(b,a,i) + u(b,i,a) + u(i,a,b) + u(i,b,a);
        int m = (a == b && b == i) ? 6 : ((a == b || b == i) ? 2 : 1);
        U3s[idx] = s / (float)m;
    } else if (idx < NTRI * P3 + NPAIR * P2) {
        int j = idx - NTRI * P3;
        int pr = j / P2, k = j % P2;
        int rem = pr, a = 0;
        while (rem >= NL - a) { rem -= NL - a; a++; }
        int b = a + rem;
        float s = U2[(a * NL + b) * P2 + k];
        if (a != b) s += U2[(b * NL + a) * P2 + k];
        U2s[pr * P2 + k] = s;
    }
}

// ---------------- Precompute: per-type coefficient tables (interleaved) -------
// A3 layout: [t][tri/4][c][4]  -> thread c reads float4 of 4 consecutive tri
// A2 layout: [t][pr/2][c][2]   -> float2 of 2 consecutive pairs
// A1 layout: [t][a][c]         -> scalar
__global__ void k_buildA(const float* __restrict__ U3s, const float* __restrict__ U2s,
                         const float* __restrict__ U1,
                         const float* __restrict__ W3, const float* __restrict__ W2,
                         const float* __restrict__ W1,
                         float* __restrict__ A3, float* __restrict__ A2, float* __restrict__ A1) {
    int b = blockIdx.x;
    int c = threadIdx.x;  // 128 threads = channels
    if (b < EE * NTRI) {
        int t = b / NTRI, tri = b % NTRI;
        float s = 0.f;
        #pragma unroll
        for (int k = 0; k < P3; k++) s += U3s[tri * P3 + k] * W3[(t * P3 + k) * CC + c];
        A3[(((size_t)t * (NTRI / 4) + (tri >> 2)) * CC + c) * 4 + (tri & 3)] = s;
    } else if (b < EE * (NTRI + NPAIR)) {
        int j = b - EE * NTRI;
        int t = j / NPAIR, pr = j % NPAIR;
        float s = 0.f;
        #pragma unroll
        for (int k = 0; k < P2; k++) s += U2s[pr * P2 + k] * W2[(t * P2 + k) * CC + c];
        A2[(((size_t)t * (NPAIR / 2) + (pr >> 1)) * CC + c) * 2 + (pr & 1)] = s;
    } else {
        int t = b - EE * (NTRI + NPAIR);
        for (int a = 0; a < NL; a++) {
            float s = 0.f;
            #pragma unroll
            for (int k = 0; k < P1; k++) s += U1[a * P1 + k] * W1[(t * P1 + k) * CC + c];
            A1[((size_t)t * NL + a) * CC + c] = s;
        }
    }
}

// ---------------- Atom bucketing by type ----------------
__global__ void k_zero(int* counts) {
    if (threadIdx.x < 16) counts[threadIdx.x] = 0;
}

__global__ void k_bucket(const int* __restrict__ types, int* counts, int* buckets, int N) {
    int n = blockIdx.x * blockDim.x + threadIdx.x;
    if (n < N) {
        int t = types[n];
        int pos = atomicAdd(&counts[t], 1);
        buckets[t * N + pos] = n;
    }
}

__global__ void k_groups(const int* __restrict__ counts, const int* __restrict__ buckets,
                         int* __restrict__ groups, int* __restrict__ ngroups, int N) {
    __shared__ int goff[EE + 1];
    if (threadIdx.x == 0) {
        int off = 0;
        for (int t = 0; t < EE; t++) { goff[t] = off; off += (counts[t] + GG - 1) / GG; }
        goff[EE] = off;
        *ngroups = off;
    }
    __syncthreads();
    for (int t = 0; t < EE; t++) {
        int cnt = counts[t];
        int ng = (cnt + GG - 1) / GG;
        for (int g = threadIdx.x; g < ng; g += blockDim.x) {
            int* gr = &groups[(goff[t] + g) * 8];
            int nv = cnt - g * GG; if (nv > GG) nv = GG;
            gr[0] = t;
            gr[5] = nv;
            for (int j = 0; j < GG; j++) {
                int jj = j < nv ? j : nv - 1;
                gr[1 + j] = buckets[t * N + g * GG + jj];
            }
        }
    }
}

// ---------------- Main: evaluate cubic form per (group-half, channel) --------
template <int A0, int A1, bool LIN>
__device__ __forceinline__ void eval_nest(const float (&xv)[GG][NL],
                                          const float4* __restrict__ a3v,
                                          const float2* __restrict__ a2v,
                                          const float* __restrict__ a1p,
                                          float (&acc)[GG]) {
    if (LIN) {
        #pragma unroll
        for (int a = 0; a < NL; a++) {
            float w = a1p[a * CC];
            #pragma unroll
            for (int g = 0; g < GG; g++) acc[g] += w * xv[g][a];
        }
    }
    float4 w4 = {0.f, 0.f, 0.f, 0.f};
    float2 wp = {0.f, 0.f};
    int tri = trisBefore(A0), pr = pairsBefore(A0);
    #pragma unroll
    for (int a = A0; a < A1; a++) {
        #pragma unroll
        for (int b = a; b < NL; b++) {
            float p[GG];
            #pragma unroll
            for (int g = 0; g < GG; g++) p[g] = xv[g][a] * xv[g][b];
            if ((pr & 1) == 0) wp = a2v[(size_t)(pr >> 1) * CC];
            float w2 = ((pr & 1) == 0) ? wp.x : wp.y;
            pr++;
            #pragma unroll
            for (int g = 0; g < GG; g++) acc[g] += w2 * p[g];
            #pragma unroll
            for (int i = b; i < NL; i++) {
                if ((tri & 3) == 0) w4 = a3v[(size_t)(tri >> 2) * CC];
                int r = tri & 3;
                float w3 = (r == 0) ? w4.x : (r == 1) ? w4.y : (r == 2) ? w4.z : w4.w;
                tri++;
                #pragma unroll
                for (int g = 0; g < GG; g++) acc[g] += w3 * (p[g] * xv[g][i]);
            }
        }
    }
}

__global__ __launch_bounds__(CC, 3) void k_main(const float* __restrict__ x,
                                                const float* __restrict__ A3,
                                                const float* __restrict__ A2,
                                                const float* __restrict__ A1,
                                                const int* __restrict__ groups,
                                                const int* __restrict__ ngroups,
                                                float* __restrict__ out) {
    int blk = blockIdx.x;
    if (blk >= *ngroups) return;
    const int* gr = groups + blk * 8;
    int t = gr[0];
    int nvalid = gr[5];
    int c = threadIdx.x;

    int na[GG];
    #pragma unroll
    for (int g = 0; g < GG; g++) na[g] = gr[1 + g];

    float xv[GG][NL];
    #pragma unroll
    for (int g = 0; g < GG; g++)
        #pragma unroll
        for (int i = 0; i < NL; i++)
            xv[g][i] = x[((size_t)na[g] * NL + i) * CC + c];

    const float4* a3v = (const float4*)A3 + (size_t)t * (NTRI / 4) * CC + c;
    const float2* a2v = (const float2*)A2 + (size_t)t * (NPAIR / 2) * CC + c;
    const float* a1p = A1 + (size_t)t * NL * CC + c;

    float acc[GG] = {0.f, 0.f, 0.f, 0.f};
    if (blockIdx.y == 0)
        eval_nest<0, ASPLIT, true>(xv, a3v, a2v, a1p, acc);
    else
        eval_nest<ASPLIT, NL, false>(xv, a3v, a2v, a1p, acc);

    #pragma unroll
    for (int g = 0; g < GG; g++)
        if (g < nvalid) atomicAdd(&out[(size_t)na[g] * CC + c], acc[g]);
}

extern "C" void kernel_launch(void* const* d_in, const int* in_sizes, int n_in,
                              void* d_out, int out_size, void* d_ws, size_t ws_size,
                              hipStream_t stream) {
    const float* x   = (const float*)d_in[0];
    const int* types = (const int*)d_in[1];
    const float* U3  = (const float*)d_in[2];
    const float* U2  = (const float*)d_in[3];
    const float* U1  = (const float*)d_in[4];
    const float* W3  = (const float*)d_in[5];
    const float* W2  = (const float*)d_in[6];
    const float* W1  = (const float*)d_in[7];
    float* out = (float*)d_out;
    int N = in_sizes[1];  // atom count (2048)

    int ngmax = (N + GG - 1) / GG + EE;  // strict upper bound on group count

    float* ws   = (float*)d_ws;
    float* U3s  = ws;                           // NTRI*P3
    float* U2s  = U3s + NTRI * P3;              // NPAIR*P2
    float* A3   = U2s + NPAIR * P2;             // EE*NTRI*CC (interleaved x4)
    float* A2   = A3 + (size_t)EE * NTRI * CC;  // EE*NPAIR*CC (interleaved x2)
    float* A1   = A2 + (size_t)EE * NPAIR * CC; // EE*NL*CC
    int* counts  = (int*)(A1 + (size_t)EE * NL * CC);  // 16
    int* buckets = counts + 16;                 // EE*N
    int* groups  = buckets + (size_t)EE * N;    // ngmax*8
    int* ngroups = groups + (size_t)ngmax * 8;

    hipMemsetAsync(out, 0, (size_t)out_size * sizeof(float), stream);

    int symThreads = NTRI * P3 + NPAIR * P2;
    hipLaunchKernelGGL(k_symU, dim3((symThreads + 255) / 256), dim3(256), 0, stream,
                       U3, U2, U3s, U2s);
    hipLaunchKernelGGL(k_buildA, dim3(EE * (NTRI + NPAIR) + EE), dim3(CC), 0, stream,
                       U3s, U2s, U1, W3, W2, W1, A3, A2, A1);
    hipLaunchKernelGGL(k_zero, dim3(1), dim3(64), 0, stream, counts);
    hipLaunchKernelGGL(k_bucket, dim3((N + 255) / 256), dim3(256), 0, stream,
                       types, counts, buckets, N);
    hipLaunchKernelGGL(k_groups, dim3(1), dim3(256), 0, stream,
                       counts, buckets, groups, ngroups, N);
    hipLaunchKernelGGL(k_main, dim3(ngmax, 2), dim3(CC), 0, stream,
                       x, A3, A2, A1, groups, ngroups, out);
}